// Round 9
// baseline (192.554 us; speedup 1.0000x reference)
//
#include <hip/hip_runtime.h>
#include <hip/hip_bf16.h>

#define G_SLOTS   8
#define D_OUT     7
#define NODE_DIM  128
#define GLOB_DIM  128
#define HIDDEN    64
#define NEG_VAL   (-1000000000.0f)
#define ROW_H     272            // halves per row; 544 B => uniform 8-per-bank b128
#define H_STRIDE  68             // f32 dwords; H row stride
#define POUT_OFF  4352           // f32 dword offset of pout inside wt (after H's 64*68)

typedef _Float16 half8 __attribute__((ext_vector_type(8)));
typedef float    f32x4 __attribute__((ext_vector_type(4)));

// ---------------- single fused kernel ----------------------------------------
// Block: 256 threads = 4 waves, 64 slots = 8 batches (b0..b0+7).
// Phase 0 (pre-barrier, overlapped): lanes 0..8 of wave 0 binary-search
//   starts_l[i] = lower_bound(batch[], b0+i); all threads stage W1^T + glob.
// xa: [64 m][256 k] f16 (node cols 0..127, glob cols 128..255), row = slot.
// wt: [64 n][256 k] f16 (W1 transposed).  C = X @ W1 via mfma_f32_16x16x32_f16.
// After MFMA (barrier), wt's space is reused: H (f32 [64][68]) at dw 0,
// pout (f32 [4][448]) at dw POUT_OFF — disjoint.
// NOTE: every per-element epilogue loop MUST block-stride by 256 — a plain
// `if (t < 448)` with 256 threads silently drops elements 256..447 (R3/R5-R7 bug).
__global__ __launch_bounds__(256) void fused_all_kernel(
        const float* __restrict__ node,
        const float* __restrict__ glob,
        const int* __restrict__ sel,
        const int* __restrict__ batch,
        const int* __restrict__ mmask,
        const float* __restrict__ W1,
        const float* __restrict__ b1,
        const float* __restrict__ W2,
        const float* __restrict__ b2,
        float* __restrict__ out, int N) {
    __shared__ __align__(16) _Float16 xa[64 * ROW_H];   // 34816 B
    __shared__ __align__(16) _Float16 wt[64 * ROW_H];   // 34816 B
    __shared__ __align__(16) int starts_l[G_SLOTS + 1];
    __shared__ __align__(16) int nidxl[64];

    int t = threadIdx.x;
    int b0 = (int)blockIdx.x * 8;
    int slot0 = (int)blockIdx.x * 64;

    // ---- phase 0a: binary search segment bounds (lanes 0..8 of wave 0) ----
    if (t < 9) {
        int target = b0 + t;
        int lo = 0, hi = N;
        while (lo < hi) {
            int mid = (lo + hi) >> 1;
            if (batch[mid] < target) lo = mid + 1; else hi = mid;
        }
        starts_l[t] = lo;
    }

    // ---- phase 0b: stage W1^T as f16: thread (n = t&63, ko8 = (t>>6)*8) ----
    {
        int n = t & 63, ko8 = (t >> 6) * 8;
#pragma unroll
        for (int it = 0; it < 8; ++it) {
            int k0 = it * 32 + ko8;
            half8 hv;
#pragma unroll
            for (int j = 0; j < 8; ++j) {
                hv[j] = (_Float16)W1[(k0 + j) * HIDDEN + n];
            }
            *(half8*)&wt[n * ROW_H + k0] = hv;
        }
    }

    // ---- phase 0c: stage glob into xa cols 128..255: (r = t>>2, q = t&3) ----
    {
        int r = t >> 2, q = t & 3;
        const float* gsrc = glob + (size_t)(b0 + (r >> 3)) * GLOB_DIM + q * 32;
        int dst = r * ROW_H + 128 + q * 32;
#pragma unroll
        for (int jj = 0; jj < 4; ++jj) {
            half8 hv;
#pragma unroll
            for (int j = 0; j < 8; ++j) {
                hv[j] = (_Float16)gsrc[jj * 8 + j];
            }
            *(half8*)&xa[dst + jj * 8] = hv;
        }
    }
    __syncthreads();

    // ---- ballot scan: wave w handles batches 2w, 2w+1 ----
    {
        int w = t >> 6, lane = t & 63;
        for (int bi = w * 2; bi < w * 2 + 2; ++bi) {
            int start = starts_l[bi], end = starts_l[bi + 1];
            int found = 0;
            for (int base = start; base < end && found < G_SLOTS; base += 64) {
                int i = base + lane;
                bool s = (i < end) && (sel[i] != 0);
                unsigned long long m = __ballot(s);
                if (s) {
                    int rank = found + __popcll(m & ((1ull << lane) - 1ull));
                    if (rank < G_SLOTS) nidxl[bi * G_SLOTS + rank] = i;
                }
                found += __popcll(m);
            }
            int f = found < G_SLOTS ? found : G_SLOTS;
            if (lane < G_SLOTS - f) nidxl[bi * G_SLOTS + f + lane] = -1;
        }
    }
    __syncthreads();

    // ---- gather node rows into xa cols 0..127 (f16) ----
    {
        int r = t >> 2, q = t & 3;
        int nidx = nidxl[r];
        int dst = r * ROW_H + q * 32;
        if (nidx >= 0) {
            const float* src = node + (size_t)nidx * NODE_DIM + q * 32;
#pragma unroll
            for (int jj = 0; jj < 4; ++jj) {
                half8 hv;
#pragma unroll
                for (int j = 0; j < 8; ++j) {
                    hv[j] = (_Float16)src[jj * 8 + j];
                }
                *(half8*)&xa[dst + jj * 8] = hv;
            }
        } else {
            half8 hz;
#pragma unroll
            for (int j = 0; j < 8; ++j) hz[j] = (_Float16)0.0f;
#pragma unroll
            for (int jj = 0; jj < 4; ++jj) *(half8*)&xa[dst + jj * 8] = hz;
        }
    }
    __syncthreads();

    // ---- MFMA: wave w owns n-tile w. A[m=lane&15][k=quad*8+j]; B likewise ----
    int w = t >> 6, lane = t & 63;
    int col = lane & 15, quad = lane >> 4;
    f32x4 acc0, acc1, acc2, acc3;
    acc0 = 0.0f; acc1 = 0.0f; acc2 = 0.0f; acc3 = 0.0f;
    {
        int nrow = w * 16 + col;
#pragma unroll
        for (int kt = 0; kt < 8; ++kt) {
            half8 bf = *(const half8*)&wt[nrow * ROW_H + kt * 32 + quad * 8];
            half8 a0 = *(const half8*)&xa[(0 * 16 + col) * ROW_H + kt * 32 + quad * 8];
            half8 a1 = *(const half8*)&xa[(1 * 16 + col) * ROW_H + kt * 32 + quad * 8];
            half8 a2 = *(const half8*)&xa[(2 * 16 + col) * ROW_H + kt * 32 + quad * 8];
            half8 a3 = *(const half8*)&xa[(3 * 16 + col) * ROW_H + kt * 32 + quad * 8];
            acc0 = __builtin_amdgcn_mfma_f32_16x16x32_f16(a0, bf, acc0, 0, 0, 0);
            acc1 = __builtin_amdgcn_mfma_f32_16x16x32_f16(a1, bf, acc1, 0, 0, 0);
            acc2 = __builtin_amdgcn_mfma_f32_16x16x32_f16(a2, bf, acc2, 0, 0, 0);
            acc3 = __builtin_amdgcn_mfma_f32_16x16x32_f16(a3, bf, acc3, 0, 0, 0);
        }
    }
    int nh = w * 16 + col;
    float b1v = b1[nh];
    __syncthreads();                  // all waves done reading xa/wt

    // ---- H = relu(C + b1) into wt-space as f32; C/D: col=lane&15, row=quad*4+reg ----
    {
        float* H = (float*)wt;
#pragma unroll
        for (int reg = 0; reg < 4; ++reg) {
            int m0 = quad * 4 + reg;
            H[(m0 +  0) * H_STRIDE + nh] = fmaxf(acc0[reg] + b1v, 0.0f);
            H[(m0 + 16) * H_STRIDE + nh] = fmaxf(acc1[reg] + b1v, 0.0f);
            H[(m0 + 32) * H_STRIDE + nh] = fmaxf(acc2[reg] + b1v, 0.0f);
            H[(m0 + 48) * H_STRIDE + nh] = fmaxf(acc3[reg] + b1v, 0.0f);
        }
    }
    __syncthreads();

    // ---- second layer: thread (sl = t&63) over hidden [partu*16, +16) ----
    {
        const float* H = (const float*)wt;
        float* pout = (float*)wt + POUT_OFF;           // disjoint from H region
        int sl = t & 63;
        int partu = t >> 6;                            // wave-uniform
        float p[D_OUT];
#pragma unroll
        for (int d = 0; d < D_OUT; ++d) p[d] = 0.0f;
#pragma unroll
        for (int jj = 0; jj < 4; ++jj) {
            float4 hq = *(const float4*)&H[sl * H_STRIDE + partu * 16 + jj * 4];
            float hv0 = hq.x, hv1 = hq.y, hv2 = hq.z, hv3 = hq.w;
            int n0 = partu * 16 + jj * 4;              // wave-uniform -> scalar loads
#pragma unroll
            for (int d = 0; d < D_OUT; ++d) {
                float s = fmaf(hv0, W2[(n0 + 0) * D_OUT + d], p[d]);
                s = fmaf(hv1, W2[(n0 + 1) * D_OUT + d], s);
                s = fmaf(hv2, W2[(n0 + 2) * D_OUT + d], s);
                s = fmaf(hv3, W2[(n0 + 3) * D_OUT + d], s);
                p[d] = s;
            }
        }
#pragma unroll
        for (int d = 0; d < D_OUT; ++d) pout[partu * 448 + sl * D_OUT + d] = p[d];
    }
    __syncthreads();

    // ---- final reduce + bias + mask + store: 448 elems, block-stride ----
    {
        const float* pout = (const float*)wt + POUT_OFF;
        for (int e = t; e < 64 * D_OUT; e += 256) {
            int sl = e / D_OUT, d = e - sl * D_OUT;
            float v = pout[e] + pout[448 + e] + pout[896 + e] + pout[1344 + e] + b2[d];
            int oidx = slot0 * D_OUT + e;
            bool ok = (nidxl[sl] >= 0) && (mmask[oidx] != 0);
            out[oidx] = ok ? v : NEG_VAL;
        }
    }
}

extern "C" void kernel_launch(void* const* d_in, const int* in_sizes, int n_in,
                              void* d_out, int out_size, void* d_ws, size_t ws_size,
                              hipStream_t stream) {
    const float* node  = (const float*)d_in[0];   // (N, 128)
    const float* glob  = (const float*)d_in[1];   // (B, 128)
    const int*   sel   = (const int*)d_in[2];     // (N,)
    const int*   batch = (const int*)d_in[3];     // (N,)
    const int*   mmask = (const int*)d_in[4];     // (B, G, D)
    const float* W1    = (const float*)d_in[5];   // (256, 64)
    const float* b1    = (const float*)d_in[6];   // (64,)
    const float* W2    = (const float*)d_in[7];   // (64, 7)
    const float* b2    = (const float*)d_in[8];   // (7,)
    float* out = (float*)d_out;

    int N = in_sizes[3];
    int B = in_sizes[1] / GLOB_DIM;

    fused_all_kernel<<<(B * G_SLOTS) / 64, 256, 0, stream>>>(
        node, glob, sel, batch, mmask, W1, b1, W2, b2, out, N);
}